// Round 2
// baseline (1322.942 us; speedup 1.0000x reference)
//
#include <hip/hip_runtime.h>
#include <math.h>

typedef __attribute__((ext_vector_type(8))) short short8;
typedef __attribute__((ext_vector_type(4))) float floatx4;
typedef __attribute__((ext_vector_type(4))) _Float16 half4;
typedef __attribute__((ext_vector_type(2))) _Float16 half2v;

__device__ __forceinline__ unsigned short f2bf(float f) {
    unsigned u = __builtin_bit_cast(unsigned, f);
    u += 0x7FFFu + ((u >> 16) & 1u);   // RNE
    return (unsigned short)(u >> 16);
}

// ---------------------------------------------------------------------------
// Weights are pre-converted ONCE per launch into bf16 tiles laid out in the
// EXACT swizzled LDS image, so conv A-staging is 2*MT async
// global_load_lds_dwordx4 per thread (R7; kept).
// ---------------------------------------------------------------------------
#define NWT 10
struct PrepAll {
    const float* src[NWT];
    unsigned int dstOff[NWT];   // ushort offset into wprep (== startG*8)
    int M[NWT], Ktot[NWT], KT[NWT], Mblk[NWT];
    int startG[NWT + 1];        // granule (short8) prefix sums
};

__global__ __launch_bounds__(256) void prep_all_k(PrepAll d, unsigned short* __restrict__ P)
{
    const int t = blockIdx.x * 256 + threadIdx.x;
    if (t >= d.startG[NWT]) return;
    int wi = 0;
#pragma unroll
    for (int i = 1; i < NWT; ++i) wi += (t >= d.startG[i]);
    const int g8   = t - d.startG[wi];
    const int Mblk = d.Mblk[wi];
    const int ksC  = d.KT[wi] >> 6;
    const int g    = g8 & 7;
    int rest = g8 >> 3;
    const int row = rest % Mblk; rest /= Mblk;
    const int ks  = rest % ksC;
    const int mb  = rest / ksC;
    const int kchunk = g ^ (row & 7);
    const int gm  = mb * Mblk + row;
    const int M = d.M[wi], Ktot = d.Ktot[wi];
    const float* __restrict__ src = d.src[wi];
    short8 v;
#pragma unroll
    for (int j = 0; j < 8; ++j) {
        int gk = ks * 64 + kchunk * 8 + j;
        float f = (gm < M && gk < Ktot) ? src[(size_t)gm * Ktot + gk] : 0.f;
        v[j] = (short)f2bf(f);
    }
    *(short8*)(P + d.dstOff[wi] + (size_t)g8 * 8) = v;
}

// Implicit-GEMM conv on bf16 MFMA: Out[z][m][n] = sum_k A[m][k]*B(k,n) + bias[m]
// MODE 0: zero-pad im2col  MODE 1: reflect-pad im2col  MODE 2: deform bilinear*sigmoid(mask)
// Tile: BM=64*MT, BN=64, BK=64. 256 threads = 4 waves.
// R8: latency-bound fix (MfmaUtil 3.8 / VALU 25 / HBM 10 / Occ 35 on stage-2 main).
//  - MODE2 & Kk==16: deform meta (packed clamped-corner base + mask-premult half4
//    weights) lives in REGISTERS, computed once per block (r==j, k-invariant).
//    Drops 13KB LDS + per-kstep ds_read->addr dependency; gathers batched 8 taps
//    (32 independent loads) for ILP.
//  - MODE2 & Kk!=16 (stage-1, Kk=49): meta computed ONCE per block into LDS
//    (was: full recompute incl. expf + 3 OM global reads per tap per k-step).
//    Weight halves in two uint planes (odd word stride -> conflict-free).
//  - MODE0 & Kk==16: zero-pad gather indices in 16 registers (MI0 LDS dropped).
template<int CIN,int KH,int KW,int STR,int PAD,int H,int W,int HO,int WO,int MODE,int MT>
__global__ __launch_bounds__(256) void conv_mfma(
    const unsigned short* __restrict__ Aprep, // pre-swizzled bf16 weight tiles
    const float* __restrict__ X,      // [Z][CIN][H][W]
    const float* __restrict__ OM,     // [Z][3*Kk][HO][WO] (deform only)
    const float* __restrict__ bias,   // [M]
    float* __restrict__ Out,          // [Z][M][HO*WO]
    int M)
{
    constexpr int Kk   = KH*KW;
    constexpr int Ktot = CIN*Kk;
    constexpr int HWc  = H*W;
    constexpr int HOWO = HO*WO;
    constexpr int KT   = (Ktot + 63) & ~63;
    constexpr int KSC  = KT >> 6;
    constexpr bool KGUARD = (Ktot % 64 != 0);
    constexpr bool M2R  = (MODE == 2) && (Kk == 16);   // deform, reg meta
    constexpr bool M2L  = (MODE == 2) && (Kk != 16);   // deform, LDS meta (once)
    constexpr bool M0R  = (MODE == 0) && (Kk == 16);   // zero-pad, reg idx
    constexpr bool MLUT = (MODE == 1) || (MODE == 0 && Kk != 16); // LDS idx table
    constexpr int KPAD = (Kk % 2 == 0) ? Kk + 1 : Kk;  // bank-friendly stride
    static_assert(KT % 64 == 0, "");

    const int z = blockIdx.z;
    const float* __restrict__ Xb  = X + (size_t)z * CIN * HWc;
    const float* __restrict__ OMb = (MODE == 2) ? (OM + (size_t)z * 3 * Kk * HOWO) : nullptr;
    float* __restrict__ Outb = Out + (size_t)z * (size_t)M * HOWO;

    const int n0   = blockIdx.x * 64;
    const int m0   = blockIdx.y * (64 * MT);
    const int tid  = threadIdx.x;
    const int lane = tid & 63;
    const int wave = tid >> 6;
    const int quad = lane >> 4;
    const int l16  = lane & 15;

    // B staging maps (needed early for reg-meta)
    const int bn2 = tid & 63;   // B: n (lane) -> coalesced gathers
    const int bkc = tid >> 6;   // B: 16-k chunk (0..3) == wave
    const int gn2 = n0 + bn2;
    const int ho2 = gn2 / WO, wo2 = gn2 % WO;

    __shared__ unsigned short As[64 * MT][64];
    __shared__ unsigned short Bs[64][64];
    __shared__ int      MIb[M2L ? 64 * KPAD : 1];
    __shared__ unsigned MW0[M2L ? 64 * KPAD : 1];
    __shared__ unsigned MW1[M2L ? 64 * KPAD : 1];
    __shared__ int      MI0[MLUT ? 64 * KPAD : 1];

    // ---- per-thread register meta (deform, Kk==16: tap r == j, k-invariant)
    int   rm_pk[M2R ? 16 : 1];
    half4 rm_w [M2R ? 16 : 1];
    if constexpr (M2R) {
#pragma unroll
        for (int j = 0; j < 16; ++j) {
            int ky = j / KW, kx = j % KW;
            float offy = OMb[(size_t)(2 * j) * HOWO + gn2];
            float offx = OMb[(size_t)(2 * j + 1) * HOWO + gn2];
            float ml   = OMb[(size_t)(2 * Kk + j) * HOWO + gn2];
            float mask = 1.f / (1.f + expf(-ml));
            float ys = (float)(ho2 * STR - PAD + ky) + offy;
            float xs = (float)(wo2 * STR - PAD + kx) + offx;
            float y0f = floorf(ys), x0f = floorf(xs);
            float dy = ys - y0f, dx = xs - x0f;
            int y0 = (int)y0f, x0 = (int)x0f;
            int yc0 = min(max(y0, 0), H - 1);
            int yc1 = min(max(y0 + 1, 0), H - 1);
            int xc0 = min(max(x0, 0), W - 1);
            int xc1 = min(max(x0 + 1, 0), W - 1);
            bool y0ok = (y0 >= 0) & (y0 < H), y1ok = (y0 + 1 >= 0) & (y0 + 1 < H);
            bool x0ok = (x0 >= 0) & (x0 < W), x1ok = (x0 + 1 >= 0) & (x0 + 1 < W);
            half4 w;
            w[0] = (_Float16)((y0ok && x0ok) ? (1.f - dy) * (1.f - dx) * mask : 0.f);
            w[1] = (_Float16)((y0ok && x1ok) ? (1.f - dy) * dx * mask : 0.f);
            w[2] = (_Float16)((y1ok && x0ok) ? dy * (1.f - dx) * mask : 0.f);
            w[3] = (_Float16)((y1ok && x1ok) ? dy * dx * mask : 0.f);
            rm_pk[j] = (yc0 * W + xc0) | ((xc1 - xc0) << 24) | ((yc1 - yc0) << 25);
            rm_w[j]  = w;
        }
    }

    // ---- per-thread register idx (zero-pad, Kk==16)
    int rix[M0R ? 16 : 1];
    if constexpr (M0R) {
#pragma unroll
        for (int j = 0; j < 16; ++j) {
            int ky = j / KW, kx = j % KW;
            int iy = ho2 * STR - PAD + ky;
            int ix = wo2 * STR - PAD + kx;
            rix[j] = (iy >= 0 && iy < H && ix >= 0 && ix < W) ? iy * W + ix : -1;
        }
    }

    // ---- one-time LDS meta: deform Kk=49 (stage 1 main). n = e&63 -> coalesced OM.
    if constexpr (M2L) {
        for (int e = tid; e < 64 * Kk; e += 256) {
            int n = e & 63, r = e >> 6;
            int gn = n0 + n, ho = gn / WO, wo = gn % WO;
            int ky = r / KW, kx = r % KW;
            float offy = OMb[(size_t)(2 * r) * HOWO + gn];
            float offx = OMb[(size_t)(2 * r + 1) * HOWO + gn];
            float ml   = OMb[(size_t)(2 * Kk + r) * HOWO + gn];
            float mask = 1.f / (1.f + expf(-ml));
            float ys = (float)(ho * STR - PAD + ky) + offy;
            float xs = (float)(wo * STR - PAD + kx) + offx;
            float y0f = floorf(ys), x0f = floorf(xs);
            float dy = ys - y0f, dx = xs - x0f;
            int y0 = (int)y0f, x0 = (int)x0f;
            int yc0 = min(max(y0, 0), H - 1);
            int yc1 = min(max(y0 + 1, 0), H - 1);
            int xc0 = min(max(x0, 0), W - 1);
            int xc1 = min(max(x0 + 1, 0), W - 1);
            bool y0ok = (y0 >= 0) & (y0 < H), y1ok = (y0 + 1 >= 0) & (y0 + 1 < H);
            bool x0ok = (x0 >= 0) & (x0 < W), x1ok = (x0 + 1 >= 0) & (x0 + 1 < W);
            half2v w01, w23;
            w01[0] = (_Float16)((y0ok && x0ok) ? (1.f - dy) * (1.f - dx) * mask : 0.f);
            w01[1] = (_Float16)((y0ok && x1ok) ? (1.f - dy) * dx * mask : 0.f);
            w23[0] = (_Float16)((y1ok && x0ok) ? dy * (1.f - dx) * mask : 0.f);
            w23[1] = (_Float16)((y1ok && x1ok) ? dy * dx * mask : 0.f);
            MIb[n * KPAD + r] = (yc0 * W + xc0) | ((xc1 - xc0) << 24) | ((yc1 - yc0) << 25);
            MW0[n * KPAD + r] = __builtin_bit_cast(unsigned, w01);
            MW1[n * KPAD + r] = __builtin_bit_cast(unsigned, w23);
        }
        __syncthreads();
    }
    if constexpr (MLUT) {
        for (int e = tid; e < 64 * Kk; e += 256) {
            int n = e & 63, r = e >> 6;
            int gn = n0 + n, ho = gn / WO, wo = gn % WO;
            int ky = r / KW, kx = r % KW;
            int idx;
            if constexpr (MODE == 0) {
                int iy = ho * STR - PAD + ky;
                int ix = wo * STR - PAD + kx;
                idx = (iy >= 0 && iy < H && ix >= 0 && ix < W) ? iy * W + ix : -1;
            } else {
                int iy = ho - PAD + ky; iy = iy < 0 ? -iy : (iy >= H ? 2 * H - 2 - iy : iy);
                int ix = wo - PAD + kx; ix = ix < 0 ? -ix : (ix >= W ? 2 * W - 2 - ix : ix);
                idx = iy * W + ix;
            }
            MI0[n * KPAD + r] = idx;
        }
        __syncthreads();
    }

    floatx4 acc[MT][4];
#pragma unroll
    for (int s = 0; s < MT; ++s)
#pragma unroll
        for (int t = 0; t < 4; ++t) acc[s][t] = (floatx4){0.f, 0.f, 0.f, 0.f};

    for (int k0 = 0; k0 < KT; k0 += 64) {
        // ---- stage A tile(s): async DMA from pre-swizzled bf16 tiles.
        // Issued FIRST so the loads fly under the B-gather work below.
        {
            const unsigned short* At =
                Aprep + ((size_t)blockIdx.y * KSC + (k0 >> 6)) * (size_t)(64 * MT * 64);
#pragma unroll
            for (int c = 0; c < 2 * MT; ++c) {
                const int chunk = c * 4 + wave;   // 1 KiB per wave-chunk
                __builtin_amdgcn_global_load_lds(
                    (const __attribute__((address_space(1))) void*)(At + (size_t)chunk * 512 + lane * 8),
                    (__attribute__((address_space(3))) void*)(&As[0][0] + chunk * 512),
                    16, 0, 0);
            }
        }

        // ---- stage B tile (sampled -> bf16 LDS), n-major
        {
            unsigned short tmp[16];
            if constexpr (M2R) {
                // ci fixed for this thread's 16-k chunk; meta in regs.
                const int ci = (k0 >> 4) + bkc;
                const float* img = Xb + (size_t)ci * HWc;
#pragma unroll
                for (int jh = 0; jh < 2; ++jh) {
                    float c0[8], c1[8], c2[8], c3[8];
#pragma unroll
                    for (int j = 0; j < 8; ++j) {
                        int p = rm_pk[jh * 8 + j];
                        int base = p & 0xFFFFFF;
                        int dxs  = (p >> 24) & 1;
                        int dys  = ((p >> 25) & 1) ? W : 0;
                        c0[j] = img[base];
                        c1[j] = img[base + dxs];
                        c2[j] = img[base + dys];
                        c3[j] = img[base + dys + dxs];
                    }
#pragma unroll
                    for (int j = 0; j < 8; ++j) {
                        half4 w = rm_w[jh * 8 + j];
                        tmp[jh * 8 + j] = f2bf((float)w[0] * c0[j] + (float)w[1] * c1[j]
                                             + (float)w[2] * c2[j] + (float)w[3] * c3[j]);
                    }
                }
            } else if constexpr (M2L) {
#pragma unroll
                for (int j = 0; j < 16; ++j) {
                    int gk = k0 + bkc * 16 + j;   // wave-uniform
                    float v = 0.f;
                    if (!KGUARD || gk < Ktot) {
                        int ci = gk / Kk, r = gk - ci * Kk;
                        int packed = MIb[bn2 * KPAD + r];
                        half2v w01 = __builtin_bit_cast(half2v, MW0[bn2 * KPAD + r]);
                        half2v w23 = __builtin_bit_cast(half2v, MW1[bn2 * KPAD + r]);
                        int base = packed & 0xFFFFFF;
                        int dxs  = (packed >> 24) & 1;
                        int dys  = ((packed >> 25) & 1) ? W : 0;
                        const float* img = Xb + (size_t)ci * HWc;
                        v = (float)w01[0] * img[base] + (float)w01[1] * img[base + dxs]
                          + (float)w23[0] * img[base + dys] + (float)w23[1] * img[base + dys + dxs];
                    }
                    tmp[j] = f2bf(v);
                }
            } else if constexpr (M0R) {
                const int ci = (k0 >> 4) + bkc;
                const float* img = Xb + (size_t)ci * HWc;
#pragma unroll
                for (int j = 0; j < 16; ++j) {
                    int idx = rix[j];
                    float v = idx >= 0 ? img[idx] : 0.f;
                    tmp[j] = f2bf(v);
                }
            } else {
#pragma unroll
                for (int j = 0; j < 16; ++j) {
                    int gk = k0 + bkc * 16 + j;
                    float v = 0.f;
                    if (!KGUARD || gk < Ktot) {
                        int ci, r;
                        if constexpr (Kk == 16) { ci = gk >> 4; r = gk & 15; }
                        else { ci = gk / Kk; r = gk - ci * Kk; }
                        int idx = MI0[bn2 * KPAD + r];
                        if (MODE == 1 || idx >= 0)
                            v = Xb[(size_t)ci * HWc + idx];
                    }
                    tmp[j] = f2bf(v);
                }
            }
            short8 s0, s1;
#pragma unroll
            for (int j = 0; j < 8; ++j) { s0[j] = (short)tmp[j]; s1[j] = (short)tmp[8 + j]; }
            const int g0 = (bkc * 2)     ^ (bn2 & 7);
            const int g1 = (bkc * 2 + 1) ^ (bn2 & 7);
            *(short8*)&Bs[bn2][g0 * 8] = s0;
            *(short8*)&Bs[bn2][g1 * 8] = s1;
        }
        __syncthreads();   // drains vmcnt (DMA) + lgkmcnt before MFMA reads

        // ---- MFMA: wave computes MT x 16(m) x 64(n), K=64
        {
            const int mrow = wave * 16 + l16;
#pragma unroll
            for (int kk = 0; kk < 2; ++kk) {
                const int kg = kk * 4 + quad;
                short8 a[MT];
#pragma unroll
                for (int s = 0; s < MT; ++s)
                    a[s] = *(const short8*)&As[s * 64 + mrow][((kg ^ (mrow & 7)) * 8)];
#pragma unroll
                for (int t = 0; t < 4; ++t) {
                    const int ncol = t * 16 + l16;
                    short8 b = *(const short8*)&Bs[ncol][((kg ^ (ncol & 7)) * 8)];
#pragma unroll
                    for (int s = 0; s < MT; ++s)
                        acc[s][t] = __builtin_amdgcn_mfma_f32_16x16x32_bf16(a[s], b, acc[s][t], 0, 0, 0);
                }
            }
        }
        __syncthreads();
    }

    // ---- epilogue: bias + store. D layout: row = quad*4+i, col = lane&15
#pragma unroll
    for (int s = 0; s < MT; ++s) {
#pragma unroll
        for (int t = 0; t < 4; ++t) {
            const int ng = n0 + t * 16 + l16;
#pragma unroll
            for (int i = 0; i < 4; ++i) {
                int mg = m0 + s * 64 + wave * 16 + quad * 4 + i;
                if (mg < M)
                    Outb[(size_t)mg * HOWO + ng] = acc[s][t][i] + bias[mg];
            }
        }
    }
}

// Instance norm over HW per (b,c) block; optional ReLU, dual-write, add-into-out.
template<bool RELU, bool DUAL, bool ADDIN>
__global__ __launch_bounds__(256) void instnorm_k(
    const float* __restrict__ in, float* __restrict__ out,
    float* __restrict__ out2, int HW)
{
    const int bc = blockIdx.x;
    const float* p = in + (size_t)bc * HW;
    float s = 0.f, ss = 0.f;
    for (int i = threadIdx.x; i < HW; i += 256) { float v = p[i]; s += v; ss += v * v; }
    __shared__ float rs[256], rq[256];
    rs[threadIdx.x] = s; rq[threadIdx.x] = ss;
    __syncthreads();
    for (int o = 128; o > 0; o >>= 1) {
        if (threadIdx.x < o) { rs[threadIdx.x] += rs[threadIdx.x + o]; rq[threadIdx.x] += rq[threadIdx.x + o]; }
        __syncthreads();
    }
    float mean = rs[0] / (float)HW;
    float var  = rq[0] / (float)HW - mean * mean;
    float inv  = rsqrtf(var + 1e-5f);
    float* q  = out + (size_t)bc * HW;
    float* q2 = DUAL ? (out2 + (size_t)bc * HW) : nullptr;
    for (int i = threadIdx.x; i < HW; i += 256) {
        float v = (p[i] - mean) * inv;
        if (RELU) v = fmaxf(v, 0.f);
        if (ADDIN) {
            q[i] = q[i] + v;
        } else {
            q[i] = v;
            if (DUAL) q2[i] = v;
        }
    }
}

extern "C" void kernel_launch(void* const* d_in, const int* in_sizes, int n_in,
                              void* d_out, int out_size, void* d_ws, size_t ws_size,
                              hipStream_t stream)
{
    const float* x      = (const float*)d_in[0];
    const float* w_off1 = (const float*)d_in[1];
    const float* b_off1 = (const float*)d_in[2];
    const float* w1     = (const float*)d_in[3];
    const float* b1     = (const float*)d_in[4];
    const float* w_off2 = (const float*)d_in[5];
    const float* b_off2 = (const float*)d_in[6];
    const float* w2     = (const float*)d_in[7];
    const float* b2     = (const float*)d_in[8];
    const float* w_off3 = (const float*)d_in[9];
    const float* b_off3 = (const float*)d_in[10];
    const float* w3     = (const float*)d_in[11];
    const float* b3     = (const float*)d_in[12];
    const float* rwa[2] = {(const float*)d_in[13], (const float*)d_in[17]};
    const float* rba[2] = {(const float*)d_in[14], (const float*)d_in[18]};
    const float* rwb[2] = {(const float*)d_in[15], (const float*)d_in[19]};
    const float* rbb[2] = {(const float*)d_in[16], (const float*)d_in[20]};

    float* out   = (float*)d_out;
    float* h_out = out;                         // [16,256,32,32]
    float* skip2 = out + 4194304;               // [16,128,64,64]
    float* skip3 = out + 4194304 + 8388608;     // [16,256,32,32]

    // workspace layout (floats). pool regions are time-multiplexed:
    //   om1  (stage 1):   pool[0        .. 9,633,792)
    //   om2  (stage 2):   pool[0        .. 3,145,728)
    //   om3  (stage 3):   pool[3,145,728.. 3,932,160)
    //   y1   (residual):  pool[0        .. 4,194,304)
    //   y2   (residual):  pool[4,194,304.. 8,388,608)
    //   wprep (whole launch, bf16): pool[9,633,792 .. 11,270,144)  (3,272,704 ushorts)
    // total = 16,777,216 + 11,270,144 floats = 112.2 MB
    float* wsf  = (float*)d_ws;
    float* h1   = wsf;                      // 16,777,216  [16,64,128,128]
    float* pool = h1 + 16777216;
    float* om1  = pool;
    float* om2  = pool;
    float* om3  = pool + 3145728;
    float* y1   = pool;
    float* y2   = pool + 4194304;
    unsigned short* wprep = (unsigned short*)(pool + 9633792);

    // ---- Weight prep: fp32 -> bf16, pre-swizzled into LDS tile image (one launch)
    {
        PrepAll pd;
        const float* srcs[NWT] = {w_off1, w1, w_off2, w2, w_off3, w3,
                                  rwa[0], rwb[0], rwa[1], rwb[1]};
        const int Ms [NWT] = {147, 64, 48, 128, 48, 256, 256, 256, 256, 256};
        const int Kts[NWT] = {147, 147, 1024, 1024, 2048, 2048, 2304, 2304, 2304, 2304};
        const int KTs[NWT] = {192, 192, 1024, 1024, 2048, 2048, 2304, 2304, 2304, 2304};
        const int Mbs[NWT] = {128, 64, 64, 128, 64, 128, 128, 128, 128, 128};
        int sg = 0;
        pd.startG[0] = 0;
        for (int i = 0; i < NWT; ++i) {
            pd.src[i] = srcs[i];
            pd.M[i] = Ms[i]; pd.Ktot[i] = Kts[i]; pd.KT[i] = KTs[i]; pd.Mblk[i] = Mbs[i];
            pd.dstOff[i] = (unsigned)sg * 8u;
            int mb = (Ms[i] + Mbs[i] - 1) / Mbs[i];
            sg += mb * (KTs[i] >> 6) * Mbs[i] * 8;
            pd.startG[i + 1] = sg;
        }
        // sg == 409,088 granules == 3,272,704 ushorts
        prep_all_k<<<dim3((sg + 255) / 256), 256, 0, stream>>>(pd, wprep);
    }
    // prepped-weight tile offsets (ushorts) — must match the loop above
    const unsigned short* pw_off1 = wprep + 0;
    const unsigned short* pw1     = wprep + 49152;
    const unsigned short* pw_off2 = wprep + 61440;
    const unsigned short* pw2     = wprep + 126976;
    const unsigned short* pw_off3 = wprep + 258048;
    const unsigned short* pw3     = wprep + 389120;
    const unsigned short* prwa[2] = {wprep + 913408,  wprep + 2093056};
    const unsigned short* prwb[2] = {wprep + 1503232, wprep + 2682880};

    // ---- Stage 1: 7x7 s1 p3, Cin=3 -> 64ch @128x128 (4-batch chunks to bound om1)
    for (int c = 0; c < 4; ++c) {
        const float* xc = x + (size_t)c * 4 * 3 * 16384;
        conv_mfma<3,7,7,1,3,128,128,128,128,0,2><<<dim3(256, 2, 4), 256, 0, stream>>>(
            pw_off1, xc, nullptr, b_off1, om1, 147);
        conv_mfma<3,7,7,1,3,128,128,128,128,2,1><<<dim3(256, 1, 4), 256, 0, stream>>>(
            pw1, xc, om1, b1, h1 + (size_t)c * 4 * 64 * 16384, 64);
    }
    instnorm_k<true,false,false><<<16 * 64, 256, 0, stream>>>(h1, h1, nullptr, 16384);

    // ---- Stage 2: 4x4 s2 p1, 64 -> 128ch @64x64
    conv_mfma<64,4,4,2,1,128,128,64,64,0,1><<<dim3(64, 1, 16), 256, 0, stream>>>(
        pw_off2, h1, nullptr, b_off2, om2, 48);
    conv_mfma<64,4,4,2,1,128,128,64,64,2,2><<<dim3(64, 1, 16), 256, 0, stream>>>(
        pw2, h1, om2, b2, skip2, 128);
    instnorm_k<true,false,false><<<16 * 128, 256, 0, stream>>>(skip2, skip2, nullptr, 4096);

    // ---- Stage 3: 4x4 s2 p1, 128 -> 256ch @32x32
    conv_mfma<128,4,4,2,1,64,64,32,32,0,1><<<dim3(16, 1, 16), 256, 0, stream>>>(
        pw_off3, skip2, nullptr, b_off3, om3, 48);
    conv_mfma<128,4,4,2,1,64,64,32,32,2,2><<<dim3(16, 2, 16), 256, 0, stream>>>(
        pw3, skip2, om3, b3, skip3, 256);
    instnorm_k<true,true,false><<<16 * 256, 256, 0, stream>>>(skip3, skip3, h_out, 1024);

    // ---- Residual blocks: reflect-pad 3x3, 256 -> 256 @32x32
    for (int r = 0; r < 2; ++r) {
        conv_mfma<256,3,3,1,1,32,32,32,32,1,2><<<dim3(16, 2, 16), 256, 0, stream>>>(
            rwa[r] ? prwa[r] : prwa[r], h_out, nullptr, rba[r], y1, 256);
        instnorm_k<true,false,false><<<16 * 256, 256, 0, stream>>>(y1, y1, nullptr, 1024);
        conv_mfma<256,3,3,1,1,32,32,32,32,1,2><<<dim3(16, 2, 16), 256, 0, stream>>>(
            prwb[r], y1, nullptr, rbb[r], y2, 256);
        instnorm_k<false,false,true><<<16 * 256, 256, 0, stream>>>(y2, h_out, nullptr, 1024);
    }
}

// Round 3
// 1173.572 us; speedup vs baseline: 1.1273x; 1.1273x over previous
//
#include <hip/hip_runtime.h>
#include <math.h>

typedef __attribute__((ext_vector_type(8))) short short8;
typedef __attribute__((ext_vector_type(4))) float floatx4;
typedef __attribute__((ext_vector_type(2))) _Float16 half2v;

__device__ __forceinline__ unsigned short f2bf(float f) {
    unsigned u = __builtin_bit_cast(unsigned, f);
    u += 0x7FFFu + ((u >> 16) & 1u);   // RNE
    return (unsigned short)(u >> 16);
}

// ---------------------------------------------------------------------------
// Weights are pre-converted ONCE per launch into bf16 tiles laid out in the
// EXACT swizzled LDS image, so conv A-staging is 2*MT async
// global_load_lds_dwordx4 per thread (R7; kept).
// perm=1 tensors use K-index k = r*4 + ci (ci==3 -> zero pad): lets the conv
// compute deform meta once per r and reuse it for all 3 input channels.
// ---------------------------------------------------------------------------
#define NWT 10
struct PrepAll {
    const float* src[NWT];
    unsigned int dstOff[NWT];   // ushort offset into wprep (== startG*8)
    int M[NWT], Ktot[NWT], KT[NWT], Mblk[NWT], srcK[NWT], perm[NWT];
    int startG[NWT + 1];        // granule (short8) prefix sums
};

__global__ __launch_bounds__(256) void prep_all_k(PrepAll d, unsigned short* __restrict__ P)
{
    const int t = blockIdx.x * 256 + threadIdx.x;
    if (t >= d.startG[NWT]) return;
    int wi = 0;
#pragma unroll
    for (int i = 1; i < NWT; ++i) wi += (t >= d.startG[i]);
    const int g8   = t - d.startG[wi];
    const int Mblk = d.Mblk[wi];
    const int ksC  = d.KT[wi] >> 6;
    const int g    = g8 & 7;
    int rest = g8 >> 3;
    const int row = rest % Mblk; rest /= Mblk;
    const int ks  = rest % ksC;
    const int mb  = rest / ksC;
    const int kchunk = g ^ (row & 7);
    const int gm  = mb * Mblk + row;
    const int M = d.M[wi], Ktot = d.Ktot[wi], srcK = d.srcK[wi], prm = d.perm[wi];
    const float* __restrict__ src = d.src[wi];
    short8 v;
#pragma unroll
    for (int j = 0; j < 8; ++j) {
        int gk = ks * 64 + kchunk * 8 + j;
        bool ok = (gm < M) && (gk < Ktot);
        int gs = gk;
        if (prm) { int ci = gk & 3, rr = gk >> 2; ok = ok && (ci < 3); gs = ci * 49 + rr; }
        float f = ok ? src[(size_t)gm * srcK + gs] : 0.f;
        v[j] = (short)f2bf(f);
    }
    *(short8*)(P + d.dstOff[wi] + (size_t)g8 * 8) = v;
}

// Implicit-GEMM conv on bf16 MFMA: Out[z][m][n] = sum_k A[m][k]*B(k,n) + bias[m]
// MODE 0: zero-pad im2col  MODE 1: reflect-pad im2col  MODE 2: deform bilinear*sigmoid(mask)
// Tile: BM=64*MT, BN=64, BK=64. 256 threads = 4 waves.
// R9 (post-R8 occupancy lesson: this kernel is gather-LATENCY bound; TLP is the
// latency hider, so meta must NOT live in persistent registers):
//  - META2 (deform Kk==16): meta in LDS (13KB, computed once per block; VGPR
//    stays ~low). Inner loop reads meta + issues 32 corner gathers per 8-tap
//    batch with SCOPED register arrays -> ILP without occupancy loss.
//  - M2P (deform Kk==49, PERM=1): K permuted to r*4+ci. Meta computed once per
//    r-group in registers (scoped), reused for 3 input channels: 3x less meta
//    VALU (expf) + 3x fewer OM reads than R7's direct path. No meta LDS.
//  - M0R / MLUT: batched index reads then unconditional clamped-address
//    gathers (select after) -> loads pipeline instead of serializing.
template<int CIN,int KH,int KW,int STR,int PAD,int H,int W,int HO,int WO,int MODE,int MT,int PERM=0>
__global__ __launch_bounds__(256) void conv_mfma(
    const unsigned short* __restrict__ Aprep, // pre-swizzled bf16 weight tiles
    const float* __restrict__ X,      // [Z][CIN][H][W]
    const float* __restrict__ OM,     // [Z][3*Kk][HO][WO] (deform only)
    const float* __restrict__ bias,   // [M]
    float* __restrict__ Out,          // [Z][M][HO*WO]
    int M)
{
    constexpr int Kk   = KH*KW;
    constexpr int Ktot = PERM ? 4*Kk : CIN*Kk;
    constexpr int HWc  = H*W;
    constexpr int HOWO = HO*WO;
    constexpr int KT   = (Ktot + 63) & ~63;
    constexpr int KSC  = KT >> 6;
    constexpr bool KGUARD = (Ktot % 64 != 0);
    constexpr bool META2 = (MODE == 2) && (Kk == 16);          // deform, LDS meta
    constexpr bool M2P   = (MODE == 2) && (PERM == 1);         // deform, perm'd K
    constexpr bool M0R   = (MODE == 0) && (Kk == 16);          // zero-pad, reg idx
    constexpr bool MLUT  = (MODE == 1) || (MODE == 0 && Kk != 16); // LDS idx table
    constexpr int KPAD = (Kk % 2 == 0) ? Kk + 1 : Kk;          // bank-friendly stride
    static_assert(KT % 64 == 0, "");
    static_assert(PERM == 0 || (MODE == 2 && CIN == 3 && Kk == 49), "");

    const int z = blockIdx.z;
    const float* __restrict__ Xb  = X + (size_t)z * CIN * HWc;
    const float* __restrict__ OMb = (MODE == 2) ? (OM + (size_t)z * 3 * Kk * HOWO) : nullptr;
    float* __restrict__ Outb = Out + (size_t)z * (size_t)M * HOWO;

    const int n0   = blockIdx.x * 64;
    const int m0   = blockIdx.y * (64 * MT);
    const int tid  = threadIdx.x;
    const int lane = tid & 63;
    const int wave = tid >> 6;
    const int quad = lane >> 4;
    const int l16  = lane & 15;

    // B staging maps
    const int bn2 = tid & 63;   // B: n (lane) -> coalesced gathers
    const int bkc = tid >> 6;   // B: 16-k chunk (0..3) == wave
    const int gn2 = n0 + bn2;
    const int ho2 = gn2 / WO, wo2 = gn2 % WO;

    __shared__ unsigned short As[64 * MT][64];
    __shared__ unsigned short Bs[64][64];
    __shared__ int   MIb[META2 ? 64 * KPAD : 1];
    __shared__ uint2 MWh[META2 ? 64 * KPAD : 1];
    __shared__ int   MI0[MLUT ? 64 * KPAD : 1];

    // ---- one-time LDS meta (deform Kk==16). n = e&63 -> coalesced OM reads.
    if constexpr (META2) {
        for (int e = tid; e < 64 * Kk; e += 256) {
            int n = e & 63, r = e >> 6;
            int gn = n0 + n, ho = gn / WO, wo = gn % WO;
            int ky = r / KW, kx = r % KW;
            float offy = OMb[(size_t)(2 * r) * HOWO + gn];
            float offx = OMb[(size_t)(2 * r + 1) * HOWO + gn];
            float ml   = OMb[(size_t)(2 * Kk + r) * HOWO + gn];
            float mask = 1.f / (1.f + expf(-ml));
            float ys = (float)(ho * STR - PAD + ky) + offy;
            float xs = (float)(wo * STR - PAD + kx) + offx;
            float y0f = floorf(ys), x0f = floorf(xs);
            float dy = ys - y0f, dx = xs - x0f;
            int y0 = (int)y0f, x0 = (int)x0f;
            int yc0 = min(max(y0, 0), H - 1);
            int yc1 = min(max(y0 + 1, 0), H - 1);
            int xc0 = min(max(x0, 0), W - 1);
            int xc1 = min(max(x0 + 1, 0), W - 1);
            bool y0ok = (y0 >= 0) & (y0 < H), y1ok = (y0 + 1 >= 0) & (y0 + 1 < H);
            bool x0ok = (x0 >= 0) & (x0 < W), x1ok = (x0 + 1 >= 0) & (x0 + 1 < W);
            half2v w01, w23;
            w01[0] = (_Float16)((y0ok && x0ok) ? (1.f - dy) * (1.f - dx) * mask : 0.f);
            w01[1] = (_Float16)((y0ok && x1ok) ? (1.f - dy) * dx * mask : 0.f);
            w23[0] = (_Float16)((y1ok && x0ok) ? dy * (1.f - dx) * mask : 0.f);
            w23[1] = (_Float16)((y1ok && x1ok) ? dy * dx * mask : 0.f);
            MIb[n * KPAD + r] = (yc0 * W + xc0) | ((xc1 - xc0) << 24) | ((yc1 - yc0) << 25);
            MWh[n * KPAD + r] = make_uint2(__builtin_bit_cast(unsigned, w01),
                                           __builtin_bit_cast(unsigned, w23));
        }
        __syncthreads();
    }
    if constexpr (MLUT) {
        for (int e = tid; e < 64 * Kk; e += 256) {
            int n = e & 63, r = e >> 6;
            int gn = n0 + n, ho = gn / WO, wo = gn % WO;
            int ky = r / KW, kx = r % KW;
            int idx;
            if constexpr (MODE == 0) {
                int iy = ho * STR - PAD + ky;
                int ix = wo * STR - PAD + kx;
                idx = (iy >= 0 && iy < H && ix >= 0 && ix < W) ? iy * W + ix : -1;
            } else {
                int iy = ho - PAD + ky; iy = iy < 0 ? -iy : (iy >= H ? 2 * H - 2 - iy : iy);
                int ix = wo - PAD + kx; ix = ix < 0 ? -ix : (ix >= W ? 2 * W - 2 - ix : ix);
                idx = iy * W + ix;
            }
            MI0[n * KPAD + r] = idx;
        }
        __syncthreads();
    }

    // ---- per-thread register idx (zero-pad, Kk==16); 16 regs, cheap kernels only
    int rix[M0R ? 16 : 1];
    if constexpr (M0R) {
#pragma unroll
        for (int j = 0; j < 16; ++j) {
            int ky = j / KW, kx = j % KW;
            int iy = ho2 * STR - PAD + ky;
            int ix = wo2 * STR - PAD + kx;
            rix[j] = (iy >= 0 && iy < H && ix >= 0 && ix < W) ? iy * W + ix : -1;
        }
    }

    floatx4 acc[MT][4];
#pragma unroll
    for (int s = 0; s < MT; ++s)
#pragma unroll
        for (int t = 0; t < 4; ++t) acc[s][t] = (floatx4){0.f, 0.f, 0.f, 0.f};

    for (int k0 = 0; k0 < KT; k0 += 64) {
        // ---- stage A tile(s): async DMA from pre-swizzled bf16 tiles.
        // Issued FIRST so the loads fly under the B-gather work below.
        {
            const unsigned short* At =
                Aprep + ((size_t)blockIdx.y * KSC + (k0 >> 6)) * (size_t)(64 * MT * 64);
#pragma unroll
            for (int c = 0; c < 2 * MT; ++c) {
                const int chunk = c * 4 + wave;   // 1 KiB per wave-chunk
                __builtin_amdgcn_global_load_lds(
                    (const __attribute__((address_space(1))) void*)(At + (size_t)chunk * 512 + lane * 8),
                    (__attribute__((address_space(3))) void*)(&As[0][0] + chunk * 512),
                    16, 0, 0);
            }
        }

        // ---- stage B tile (sampled -> bf16 LDS), n-major
        {
            unsigned short tmp[16];
            if constexpr (META2) {
                // ci fixed per thread; meta from LDS in scoped 8-tap batches.
                const int ci = (k0 >> 4) + bkc;
                const float* img = Xb + (size_t)ci * HWc;
                const int mb = bn2 * KPAD;
#pragma unroll
                for (int jh = 0; jh < 2; ++jh) {
                    int pk[8]; unsigned wa[8], wb[8];
#pragma unroll
                    for (int j = 0; j < 8; ++j) pk[j] = MIb[mb + jh * 8 + j];
#pragma unroll
                    for (int j = 0; j < 8; ++j) {
                        uint2 ww = MWh[mb + jh * 8 + j];
                        wa[j] = ww.x; wb[j] = ww.y;
                    }
                    float c0[8], c1[8], c2[8], c3[8];
#pragma unroll
                    for (int j = 0; j < 8; ++j) {
                        int p = pk[j];
                        int base = p & 0xFFFFFF;
                        int dxs  = (p >> 24) & 1;
                        int dys  = ((p >> 25) & 1) ? W : 0;
                        c0[j] = img[base];
                        c1[j] = img[base + dxs];
                        c2[j] = img[base + dys];
                        c3[j] = img[base + dys + dxs];
                    }
#pragma unroll
                    for (int j = 0; j < 8; ++j) {
                        half2v w01 = __builtin_bit_cast(half2v, wa[j]);
                        half2v w23 = __builtin_bit_cast(half2v, wb[j]);
                        tmp[jh * 8 + j] = f2bf((float)w01[0] * c0[j] + (float)w01[1] * c1[j]
                                             + (float)w23[0] * c2[j] + (float)w23[1] * c3[j]);
                    }
                }
            } else if constexpr (M2P) {
                // perm'd K: groups of 4 slots share one r (meta computed once,
                // reused for 3 input planes; slot 3 is zero padding).
                const int kbase = k0 + bkc * 16;   // % 4 == 0
                const int rbase = kbase >> 2;
#pragma unroll
                for (int u = 0; u < 4; ++u) {
                    const int r = rbase + u;       // wave-uniform
                    float v0 = 0.f, v1 = 0.f, v2 = 0.f;
                    if (r < Kk) {
                        const int ky = r / KW, kx = r - ky * KW;
                        float offy = OMb[(size_t)(2 * r) * HOWO + gn2];
                        float offx = OMb[(size_t)(2 * r + 1) * HOWO + gn2];
                        float ml   = OMb[(size_t)(2 * Kk + r) * HOWO + gn2];
                        float mask = 1.f / (1.f + expf(-ml));
                        float ys = (float)(ho2 * STR - PAD + ky) + offy;
                        float xs = (float)(wo2 * STR - PAD + kx) + offx;
                        float y0f = floorf(ys), x0f = floorf(xs);
                        float dy = ys - y0f, dx = xs - x0f;
                        int y0 = (int)y0f, x0 = (int)x0f;
                        int yc0 = min(max(y0, 0), H - 1);
                        int yc1 = min(max(y0 + 1, 0), H - 1);
                        int xc0 = min(max(x0, 0), W - 1);
                        int xc1 = min(max(x0 + 1, 0), W - 1);
                        bool y0ok = (y0 >= 0) & (y0 < H), y1ok = (y0 + 1 >= 0) & (y0 + 1 < H);
                        bool x0ok = (x0 >= 0) & (x0 < W), x1ok = (x0 + 1 >= 0) & (x0 + 1 < W);
                        float w00 = (y0ok && x0ok) ? (1.f - dy) * (1.f - dx) * mask : 0.f;
                        float w01 = (y0ok && x1ok) ? (1.f - dy) * dx * mask : 0.f;
                        float w10 = (y1ok && x0ok) ? dy * (1.f - dx) * mask : 0.f;
                        float w11 = (y1ok && x1ok) ? dy * dx * mask : 0.f;
                        int base = yc0 * W + xc0;
                        int dxs  = xc1 - xc0;
                        int dys  = (yc1 - yc0) ? W : 0;
                        float cc[12];
#pragma unroll
                        for (int ci = 0; ci < 3; ++ci) {
                            const float* img = Xb + (size_t)ci * HWc;
                            cc[ci * 4 + 0] = img[base];
                            cc[ci * 4 + 1] = img[base + dxs];
                            cc[ci * 4 + 2] = img[base + dys];
                            cc[ci * 4 + 3] = img[base + dys + dxs];
                        }
                        v0 = w00 * cc[0] + w01 * cc[1] + w10 * cc[2]  + w11 * cc[3];
                        v1 = w00 * cc[4] + w01 * cc[5] + w10 * cc[6]  + w11 * cc[7];
                        v2 = w00 * cc[8] + w01 * cc[9] + w10 * cc[10] + w11 * cc[11];
                    }
                    tmp[u * 4 + 0] = f2bf(v0);
                    tmp[u * 4 + 1] = f2bf(v1);
                    tmp[u * 4 + 2] = f2bf(v2);
                    tmp[u * 4 + 3] = 0;
                }
            } else if constexpr (M0R) {
                const int ci = (k0 >> 4) + bkc;
                const float* img = Xb + (size_t)ci * HWc;
                float raw[16];
#pragma unroll
                for (int j = 0; j < 16; ++j) raw[j] = img[rix[j] < 0 ? 0 : rix[j]];
#pragma unroll
                for (int j = 0; j < 16; ++j) tmp[j] = rix[j] < 0 ? (unsigned short)0 : f2bf(raw[j]);
            } else {
                // MLUT: batched idx reads then unconditional clamped gathers
                int idxs[16], cis[16];
#pragma unroll
                for (int j = 0; j < 16; ++j) {
                    int gk = k0 + bkc * 16 + j;
                    int ci = (Kk == 16) ? (gk >> 4) : gk / Kk;
                    int r  = gk - ci * Kk;
                    int idx = MI0[bn2 * KPAD + r];
                    if (KGUARD && gk >= Ktot) idx = -1;
                    idxs[j] = idx; cis[j] = ci;
                }
                float raw[16];
#pragma unroll
                for (int j = 0; j < 16; ++j)
                    raw[j] = Xb[(size_t)cis[j] * HWc + (idxs[j] < 0 ? 0 : idxs[j])];
#pragma unroll
                for (int j = 0; j < 16; ++j)
                    tmp[j] = idxs[j] < 0 ? (unsigned short)0 : f2bf(raw[j]);
            }
            short8 s0, s1;
#pragma unroll
            for (int j = 0; j < 8; ++j) { s0[j] = (short)tmp[j]; s1[j] = (short)tmp[8 + j]; }
            const int g0 = (bkc * 2)     ^ (bn2 & 7);
            const int g1 = (bkc * 2 + 1) ^ (bn2 & 7);
            *(short8*)&Bs[bn2][g0 * 8] = s0;
            *(short8*)&Bs[bn2][g1 * 8] = s1;
        }
        __syncthreads();   // drains vmcnt (DMA) + lgkmcnt before MFMA reads

        // ---- MFMA: wave computes MT x 16(m) x 64(n), K=64
        {
            const int mrow = wave * 16 + l16;
#pragma unroll
            for (int kk = 0; kk < 2; ++kk) {
                const int kg = kk * 4 + quad;
                short8 a[MT];
#pragma unroll
                for (int s = 0; s < MT; ++s)
                    a[s] = *(const short8*)&As[s * 64 + mrow][((kg ^ (mrow & 7)) * 8)];
#pragma unroll
                for (int t = 0; t < 4; ++t) {
                    const int ncol = t * 16 + l16;
                    short8 b = *(const short8*)&Bs[ncol][((kg ^ (ncol & 7)) * 8)];
#pragma unroll
                    for (int s = 0; s < MT; ++s)
                        acc[s][t] = __builtin_amdgcn_mfma_f32_16x16x32_bf16(a[s], b, acc[s][t], 0, 0, 0);
                }
            }
        }
        __syncthreads();
    }

    // ---- epilogue: bias + store. D layout: row = quad*4+i, col = lane&15
#pragma unroll
    for (int s = 0; s < MT; ++s) {
#pragma unroll
        for (int t = 0; t < 4; ++t) {
            const int ng = n0 + t * 16 + l16;
#pragma unroll
            for (int i = 0; i < 4; ++i) {
                int mg = m0 + s * 64 + wave * 16 + quad * 4 + i;
                if (mg < M)
                    Outb[(size_t)mg * HOWO + ng] = acc[s][t][i] + bias[mg];
            }
        }
    }
}

// Instance norm over HW per (b,c) block; optional ReLU, dual-write, add-into-out.
// float4 vectorized (HW % 1024 == 0 for all call sites).
template<bool RELU, bool DUAL, bool ADDIN>
__global__ __launch_bounds__(256) void instnorm_k(
    const float* __restrict__ in, float* __restrict__ out,
    float* __restrict__ out2, int HW)
{
    const int bc = blockIdx.x;
    const float4* p4 = (const float4*)(in + (size_t)bc * HW);
    const int n4 = HW >> 2;
    float s = 0.f, ss = 0.f;
    for (int i = threadIdx.x; i < n4; i += 256) {
        float4 v = p4[i];
        s  += v.x + v.y + v.z + v.w;
        ss += v.x * v.x + v.y * v.y + v.z * v.z + v.w * v.w;
    }
    __shared__ float rs[256], rq[256];
    rs[threadIdx.x] = s; rq[threadIdx.x] = ss;
    __syncthreads();
    for (int o = 128; o > 0; o >>= 1) {
        if (threadIdx.x < o) { rs[threadIdx.x] += rs[threadIdx.x + o]; rq[threadIdx.x] += rq[threadIdx.x + o]; }
        __syncthreads();
    }
    float mean = rs[0] / (float)HW;
    float var  = rq[0] / (float)HW - mean * mean;
    float inv  = rsqrtf(var + 1e-5f);
    float4* q4  = (float4*)(out + (size_t)bc * HW);
    float4* q24 = DUAL ? (float4*)(out2 + (size_t)bc * HW) : nullptr;
    for (int i = threadIdx.x; i < n4; i += 256) {
        float4 v = p4[i];
        v.x = (v.x - mean) * inv; v.y = (v.y - mean) * inv;
        v.z = (v.z - mean) * inv; v.w = (v.w - mean) * inv;
        if (RELU) {
            v.x = fmaxf(v.x, 0.f); v.y = fmaxf(v.y, 0.f);
            v.z = fmaxf(v.z, 0.f); v.w = fmaxf(v.w, 0.f);
        }
        if (ADDIN) {
            float4 o = q4[i];
            o.x += v.x; o.y += v.y; o.z += v.z; o.w += v.w;
            q4[i] = o;
        } else {
            q4[i] = v;
            if (DUAL) q24[i] = v;
        }
    }
}

extern "C" void kernel_launch(void* const* d_in, const int* in_sizes, int n_in,
                              void* d_out, int out_size, void* d_ws, size_t ws_size,
                              hipStream_t stream)
{
    const float* x      = (const float*)d_in[0];
    const float* w_off1 = (const float*)d_in[1];
    const float* b_off1 = (const float*)d_in[2];
    const float* w1     = (const float*)d_in[3];
    const float* b1     = (const float*)d_in[4];
    const float* w_off2 = (const float*)d_in[5];
    const float* b_off2 = (const float*)d_in[6];
    const float* w2     = (const float*)d_in[7];
    const float* b2     = (const float*)d_in[8];
    const float* w_off3 = (const float*)d_in[9];
    const float* b_off3 = (const float*)d_in[10];
    const float* w3     = (const float*)d_in[11];
    const float* b3     = (const float*)d_in[12];
    const float* rwa[2] = {(const float*)d_in[13], (const float*)d_in[17]};
    const float* rba[2] = {(const float*)d_in[14], (const float*)d_in[18]};
    const float* rwb[2] = {(const float*)d_in[15], (const float*)d_in[19]};
    const float* rbb[2] = {(const float*)d_in[16], (const float*)d_in[20]};

    float* out   = (float*)d_out;
    float* h_out = out;                         // [16,256,32,32]
    float* skip2 = out + 4194304;               // [16,128,64,64]
    float* skip3 = out + 4194304 + 8388608;     // [16,256,32,32]

    // workspace layout (floats). pool regions are time-multiplexed:
    //   om1  (stage 1):   pool[0 .. 9,633,792)
    //   om2  (stage 2):   pool[0 .. 3,145,728)
    //   om3  (stage 3):   pool[3,145,728 .. 3,932,160)
    //   y1/y2 (residual): pool[0 .. 8,388,608)
    //   wprep (whole launch, bf16): pool[9,633,792 .. 11,272,192)
    // total = 16,777,216 + 11,272,192 floats = 112.2 MB
    float* wsf  = (float*)d_ws;
    float* h1   = wsf;                      // 16,777,216  [16,64,128,128]
    float* pool = h1 + 16777216;
    float* om1  = pool;
    float* om2  = pool;
    float* om3  = pool + 3145728;
    float* y1   = pool;
    float* y2   = pool + 4194304;
    unsigned short* wprep = (unsigned short*)(pool + 9633792);

    // ---- Weight prep: fp32 -> bf16, pre-swizzled into LDS tile image (one launch)
    {
        PrepAll pd;
        const float* srcs[NWT] = {w_off1, w1, w_off2, w2, w_off3, w3,
                                  rwa[0], rwb[0], rwa[1], rwb[1]};
        const int Ms  [NWT] = {147, 64, 48, 128, 48, 256, 256, 256, 256, 256};
        const int Kts [NWT] = {147, 196, 1024, 1024, 2048, 2048, 2304, 2304, 2304, 2304};
        const int KTs [NWT] = {192, 256, 1024, 1024, 2048, 2048, 2304, 2304, 2304, 2304};
        const int Mbs [NWT] = {128, 64, 64, 128, 64, 128, 128, 128, 128, 128};
        const int sKs [NWT] = {147, 147, 1024, 1024, 2048, 2048, 2304, 2304, 2304, 2304};
        const int prm [NWT] = {0, 1, 0, 0, 0, 0, 0, 0, 0, 0};
        int sg = 0;
        pd.startG[0] = 0;
        for (int i = 0; i < NWT; ++i) {
            pd.src[i] = srcs[i];
            pd.M[i] = Ms[i]; pd.Ktot[i] = Kts[i]; pd.KT[i] = KTs[i];
            pd.Mblk[i] = Mbs[i]; pd.srcK[i] = sKs[i]; pd.perm[i] = prm[i];
            pd.dstOff[i] = (unsigned)sg * 8u;
            int mb = (Ms[i] + Mbs[i] - 1) / Mbs[i];
            sg += mb * (KTs[i] >> 6) * Mbs[i] * 8;
            pd.startG[i + 1] = sg;
        }
        // sg == 409,600 granules == 3,276,800 ushorts
        prep_all_k<<<dim3((sg + 255) / 256), 256, 0, stream>>>(pd, wprep);
    }
    // prepped-weight tile offsets (ushorts) — must match the loop above
    const unsigned short* pw_off1 = wprep + 0;
    const unsigned short* pw1     = wprep + 49152;
    const unsigned short* pw_off2 = wprep + 65536;
    const unsigned short* pw2     = wprep + 131072;
    const unsigned short* pw_off3 = wprep + 262144;
    const unsigned short* pw3     = wprep + 393216;
    const unsigned short* prwa[2] = {wprep + 917504,  wprep + 2097152};
    const unsigned short* prwb[2] = {wprep + 1507328, wprep + 2686976};

    // ---- Stage 1: 7x7 s1 p3, Cin=3 -> 64ch @128x128 (4-batch chunks to bound om1)
    for (int c = 0; c < 4; ++c) {
        const float* xc = x + (size_t)c * 4 * 3 * 16384;
        conv_mfma<3,7,7,1,3,128,128,128,128,0,2><<<dim3(256, 2, 4), 256, 0, stream>>>(
            pw_off1, xc, nullptr, b_off1, om1, 147);
        conv_mfma<3,7,7,1,3,128,128,128,128,2,1,1><<<dim3(256, 1, 4), 256, 0, stream>>>(
            pw1, xc, om1, b1, h1 + (size_t)c * 4 * 64 * 16384, 64);
    }
    instnorm_k<true,false,false><<<16 * 64, 256, 0, stream>>>(h1, h1, nullptr, 16384);

    // ---- Stage 2: 4x4 s2 p1, 64 -> 128ch @64x64
    conv_mfma<64,4,4,2,1,128,128,64,64,0,1><<<dim3(64, 1, 16), 256, 0, stream>>>(
        pw_off2, h1, nullptr, b_off2, om2, 48);
    conv_mfma<64,4,4,2,1,128,128,64,64,2,2><<<dim3(64, 1, 16), 256, 0, stream>>>(
        pw2, h1, om2, b2, skip2, 128);
    instnorm_k<true,false,false><<<16 * 128, 256, 0, stream>>>(skip2, skip2, nullptr, 4096);

    // ---- Stage 3: 4x4 s2 p1, 128 -> 256ch @32x32
    conv_mfma<128,4,4,2,1,64,64,32,32,0,1><<<dim3(16, 1, 16), 256, 0, stream>>>(
        pw_off3, skip2, nullptr, b_off3, om3, 48);
    conv_mfma<128,4,4,2,1,64,64,32,32,2,2><<<dim3(16, 2, 16), 256, 0, stream>>>(
        pw3, skip2, om3, b3, skip3, 256);
    instnorm_k<true,true,false><<<16 * 256, 256, 0, stream>>>(skip3, skip3, h_out, 1024);

    // ---- Residual blocks: reflect-pad 3x3, 256 -> 256 @32x32
    for (int r = 0; r < 2; ++r) {
        conv_mfma<256,3,3,1,1,32,32,32,32,1,2><<<dim3(16, 2, 16), 256, 0, stream>>>(
            prwa[r], h_out, nullptr, rba[r], y1, 256);
        instnorm_k<true,false,false><<<16 * 256, 256, 0, stream>>>(y1, y1, nullptr, 1024);
        conv_mfma<256,3,3,1,1,32,32,32,32,1,2><<<dim3(16, 2, 16), 256, 0, stream>>>(
            prwb[r], y1, nullptr, rbb[r], y2, 256);
        instnorm_k<false,false,true><<<16 * 256, 256, 0, stream>>>(y2, h_out, nullptr, 1024);
    }
}

// Round 4
// 1093.093 us; speedup vs baseline: 1.2103x; 1.0736x over previous
//
#include <hip/hip_runtime.h>
#include <math.h>

typedef __attribute__((ext_vector_type(8))) short short8;
typedef __attribute__((ext_vector_type(4))) float floatx4;
typedef __attribute__((ext_vector_type(2))) _Float16 half2v;

__device__ __forceinline__ unsigned short f2bf(float f) {
    unsigned u = __builtin_bit_cast(unsigned, f);
    u += 0x7FFFu + ((u >> 16) & 1u);   // RNE
    return (unsigned short)(u >> 16);
}

// ---------------------------------------------------------------------------
// Weights are pre-converted ONCE per launch into bf16 tiles laid out in the
// EXACT swizzled LDS image, so conv A-staging is 2*MT async
// global_load_lds_dwordx4 per thread (R7; kept).
// perm=1 tensors use K-index k = r*4 + ci (ci==3 -> zero pad): lets the conv
// compute deform meta once per r and reuse it for all 3 input channels.
// ---------------------------------------------------------------------------
#define NWT 10
struct PrepAll {
    const float* src[NWT];
    unsigned int dstOff[NWT];   // ushort offset into wprep (== startG*8)
    int M[NWT], Ktot[NWT], KT[NWT], Mblk[NWT], srcK[NWT], perm[NWT];
    int startG[NWT + 1];        // granule (short8) prefix sums
};

__global__ __launch_bounds__(256) void prep_all_k(PrepAll d, unsigned short* __restrict__ P)
{
    const int t = blockIdx.x * 256 + threadIdx.x;
    if (t >= d.startG[NWT]) return;
    int wi = 0;
#pragma unroll
    for (int i = 1; i < NWT; ++i) wi += (t >= d.startG[i]);
    const int g8   = t - d.startG[wi];
    const int Mblk = d.Mblk[wi];
    const int ksC  = d.KT[wi] >> 6;
    const int g    = g8 & 7;
    int rest = g8 >> 3;
    const int row = rest % Mblk; rest /= Mblk;
    const int ks  = rest % ksC;
    const int mb  = rest / ksC;
    const int kchunk = g ^ (row & 7);
    const int gm  = mb * Mblk + row;
    const int M = d.M[wi], Ktot = d.Ktot[wi], srcK = d.srcK[wi], prm = d.perm[wi];
    const float* __restrict__ src = d.src[wi];
    short8 v;
#pragma unroll
    for (int j = 0; j < 8; ++j) {
        int gk = ks * 64 + kchunk * 8 + j;
        bool ok = (gm < M) && (gk < Ktot);
        int gs = gk;
        if (prm) { int ci = gk & 3, rr = gk >> 2; ok = ok && (ci < 3); gs = ci * 49 + rr; }
        float f = ok ? src[(size_t)gm * srcK + gs] : 0.f;
        v[j] = (short)f2bf(f);
    }
    *(short8*)(P + d.dstOff[wi] + (size_t)g8 * 8) = v;
}

// Implicit-GEMM conv on bf16 MFMA: Out[z][m][n] = sum_k A[m][k]*B(k,n) + bias[m]
// MODE 0: zero-pad im2col  MODE 1: reflect-pad im2col  MODE 2: deform bilinear*sigmoid(mask)
// Tile: BM=64*MT, BN=64, BK=64. 256 threads = 4 waves.
// R9: meta in LDS once per block; scoped batched gathers (ILP w/o occupancy loss).
// R10: NKS k-range split for small-grid convs (@32x32 geometry had only 1-2
//      blocks/CU -> latency-bound, Occ 19%). blockIdx.y = mtile + mtiles*ks;
//      each slice writes a bias-less partial plane (Out + ks*PS); a float4
//      reduce kernel sums partials + bias. Total work constant, TLP x NKS.
template<int CIN,int KH,int KW,int STR,int PAD,int H,int W,int HO,int WO,int MODE,int MT,int PERM=0,int NKS=1>
__global__ __launch_bounds__(256) void conv_mfma(
    const unsigned short* __restrict__ Aprep, // pre-swizzled bf16 weight tiles
    const float* __restrict__ X,      // [Z][CIN][H][W]
    const float* __restrict__ OM,     // [Z][3*Kk][HO][WO] (deform only)
    const float* __restrict__ bias,   // [M] (ignored when NKS>1)
    float* __restrict__ Out,          // [Z][M][HO*WO] (or NKS partial planes)
    int M)
{
    constexpr int Kk   = KH*KW;
    constexpr int Ktot = PERM ? 4*Kk : CIN*Kk;
    constexpr int HWc  = H*W;
    constexpr int HOWO = HO*WO;
    constexpr int KT   = (Ktot + 63) & ~63;
    constexpr int KSC  = KT >> 6;
    constexpr int KSLICE = KT / NKS;
    constexpr bool KGUARD = (Ktot % 64 != 0);
    constexpr bool META2 = (MODE == 2) && (Kk == 16);          // deform, LDS meta
    constexpr bool M2P   = (MODE == 2) && (PERM == 1);         // deform, perm'd K
    constexpr bool M0R   = (MODE == 0) && (Kk == 16);          // zero-pad, reg idx
    constexpr bool MLUT  = (MODE == 1) || (MODE == 0 && Kk != 16); // LDS idx table
    constexpr int KPAD = (Kk % 2 == 0) ? Kk + 1 : Kk;          // bank-friendly stride
    static_assert(KT % (64 * NKS) == 0, "");
    static_assert(PERM == 0 || (MODE == 2 && CIN == 3 && Kk == 49), "");

    const int z = blockIdx.z;
    const float* __restrict__ Xb  = X + (size_t)z * CIN * HWc;
    const float* __restrict__ OMb = (MODE == 2) ? (OM + (size_t)z * 3 * Kk * HOWO) : nullptr;

    const int mtiles = gridDim.y / NKS;
    const int my = (NKS > 1) ? (blockIdx.y % mtiles) : blockIdx.y;
    const int ks = (NKS > 1) ? (blockIdx.y / mtiles) : 0;

    float* __restrict__ Outb;
    if constexpr (NKS > 1) {
        const size_t PS = (size_t)gridDim.z * (size_t)M * HOWO;
        Outb = Out + (size_t)ks * PS + (size_t)z * (size_t)M * HOWO;
    } else {
        Outb = Out + (size_t)z * (size_t)M * HOWO;
    }

    const int n0   = blockIdx.x * 64;
    const int m0   = my * (64 * MT);
    const int tid  = threadIdx.x;
    const int lane = tid & 63;
    const int wave = tid >> 6;
    const int quad = lane >> 4;
    const int l16  = lane & 15;

    // B staging maps
    const int bn2 = tid & 63;   // B: n (lane) -> coalesced gathers
    const int bkc = tid >> 6;   // B: 16-k chunk (0..3) == wave
    const int gn2 = n0 + bn2;
    const int ho2 = gn2 / WO, wo2 = gn2 % WO;

    __shared__ unsigned short As[64 * MT][64];
    __shared__ unsigned short Bs[64][64];
    __shared__ int   MIb[META2 ? 64 * KPAD : 1];
    __shared__ uint2 MWh[META2 ? 64 * KPAD : 1];
    __shared__ int   MI0[MLUT ? 64 * KPAD : 1];

    // ---- one-time LDS meta (deform Kk==16). n = e&63 -> coalesced OM reads.
    if constexpr (META2) {
        for (int e = tid; e < 64 * Kk; e += 256) {
            int n = e & 63, r = e >> 6;
            int gn = n0 + n, ho = gn / WO, wo = gn % WO;
            int ky = r / KW, kx = r % KW;
            float offy = OMb[(size_t)(2 * r) * HOWO + gn];
            float offx = OMb[(size_t)(2 * r + 1) * HOWO + gn];
            float ml   = OMb[(size_t)(2 * Kk + r) * HOWO + gn];
            float mask = 1.f / (1.f + expf(-ml));
            float ys = (float)(ho * STR - PAD + ky) + offy;
            float xs = (float)(wo * STR - PAD + kx) + offx;
            float y0f = floorf(ys), x0f = floorf(xs);
            float dy = ys - y0f, dx = xs - x0f;
            int y0 = (int)y0f, x0 = (int)x0f;
            int yc0 = min(max(y0, 0), H - 1);
            int yc1 = min(max(y0 + 1, 0), H - 1);
            int xc0 = min(max(x0, 0), W - 1);
            int xc1 = min(max(x0 + 1, 0), W - 1);
            bool y0ok = (y0 >= 0) & (y0 < H), y1ok = (y0 + 1 >= 0) & (y0 + 1 < H);
            bool x0ok = (x0 >= 0) & (x0 < W), x1ok = (x0 + 1 >= 0) & (x0 + 1 < W);
            half2v w01, w23;
            w01[0] = (_Float16)((y0ok && x0ok) ? (1.f - dy) * (1.f - dx) * mask : 0.f);
            w01[1] = (_Float16)((y0ok && x1ok) ? (1.f - dy) * dx * mask : 0.f);
            w23[0] = (_Float16)((y1ok && x0ok) ? dy * (1.f - dx) * mask : 0.f);
            w23[1] = (_Float16)((y1ok && x1ok) ? dy * dx * mask : 0.f);
            MIb[n * KPAD + r] = (yc0 * W + xc0) | ((xc1 - xc0) << 24) | ((yc1 - yc0) << 25);
            MWh[n * KPAD + r] = make_uint2(__builtin_bit_cast(unsigned, w01),
                                           __builtin_bit_cast(unsigned, w23));
        }
        __syncthreads();
    }
    if constexpr (MLUT) {
        for (int e = tid; e < 64 * Kk; e += 256) {
            int n = e & 63, r = e >> 6;
            int gn = n0 + n, ho = gn / WO, wo = gn % WO;
            int ky = r / KW, kx = r % KW;
            int idx;
            if constexpr (MODE == 0) {
                int iy = ho * STR - PAD + ky;
                int ix = wo * STR - PAD + kx;
                idx = (iy >= 0 && iy < H && ix >= 0 && ix < W) ? iy * W + ix : -1;
            } else {
                int iy = ho - PAD + ky; iy = iy < 0 ? -iy : (iy >= H ? 2 * H - 2 - iy : iy);
                int ix = wo - PAD + kx; ix = ix < 0 ? -ix : (ix >= W ? 2 * W - 2 - ix : ix);
                idx = iy * W + ix;
            }
            MI0[n * KPAD + r] = idx;
        }
        __syncthreads();
    }

    // ---- per-thread register idx (zero-pad, Kk==16); 16 regs, cheap kernels only
    int rix[M0R ? 16 : 1];
    if constexpr (M0R) {
#pragma unroll
        for (int j = 0; j < 16; ++j) {
            int ky = j / KW, kx = j % KW;
            int iy = ho2 * STR - PAD + ky;
            int ix = wo2 * STR - PAD + kx;
            rix[j] = (iy >= 0 && iy < H && ix >= 0 && ix < W) ? iy * W + ix : -1;
        }
    }

    floatx4 acc[MT][4];
#pragma unroll
    for (int s = 0; s < MT; ++s)
#pragma unroll
        for (int t = 0; t < 4; ++t) acc[s][t] = (floatx4){0.f, 0.f, 0.f, 0.f};

    for (int k0 = ks * KSLICE; k0 < ks * KSLICE + KSLICE; k0 += 64) {
        // ---- stage A tile(s): async DMA from pre-swizzled bf16 tiles.
        // Issued FIRST so the loads fly under the B-gather work below.
        {
            const unsigned short* At =
                Aprep + ((size_t)my * KSC + (k0 >> 6)) * (size_t)(64 * MT * 64);
#pragma unroll
            for (int c = 0; c < 2 * MT; ++c) {
                const int chunk = c * 4 + wave;   // 1 KiB per wave-chunk
                __builtin_amdgcn_global_load_lds(
                    (const __attribute__((address_space(1))) void*)(At + (size_t)chunk * 512 + lane * 8),
                    (__attribute__((address_space(3))) void*)(&As[0][0] + chunk * 512),
                    16, 0, 0);
            }
        }

        // ---- stage B tile (sampled -> bf16 LDS), n-major
        {
            unsigned short tmp[16];
            if constexpr (META2) {
                // ci fixed per thread; meta from LDS in scoped 8-tap batches.
                const int ci = (k0 >> 4) + bkc;
                const float* img = Xb + (size_t)ci * HWc;
                const int mb = bn2 * KPAD;
#pragma unroll
                for (int jh = 0; jh < 2; ++jh) {
                    int pk[8]; unsigned wa[8], wb[8];
#pragma unroll
                    for (int j = 0; j < 8; ++j) pk[j] = MIb[mb + jh * 8 + j];
#pragma unroll
                    for (int j = 0; j < 8; ++j) {
                        uint2 ww = MWh[mb + jh * 8 + j];
                        wa[j] = ww.x; wb[j] = ww.y;
                    }
                    float c0[8], c1[8], c2[8], c3[8];
#pragma unroll
                    for (int j = 0; j < 8; ++j) {
                        int p = pk[j];
                        int base = p & 0xFFFFFF;
                        int dxs  = (p >> 24) & 1;
                        int dys  = ((p >> 25) & 1) ? W : 0;
                        c0[j] = img[base];
                        c1[j] = img[base + dxs];
                        c2[j] = img[base + dys];
                        c3[j] = img[base + dys + dxs];
                    }
#pragma unroll
                    for (int j = 0; j < 8; ++j) {
                        half2v w01 = __builtin_bit_cast(half2v, wa[j]);
                        half2v w23 = __builtin_bit_cast(half2v, wb[j]);
                        tmp[jh * 8 + j] = f2bf((float)w01[0] * c0[j] + (float)w01[1] * c1[j]
                                             + (float)w23[0] * c2[j] + (float)w23[1] * c3[j]);
                    }
                }
            } else if constexpr (M2P) {
                // perm'd K: groups of 4 slots share one r (meta computed once,
                // reused for 3 input planes; slot 3 is zero padding).
                const int kbase = k0 + bkc * 16;   // % 4 == 0
                const int rbase = kbase >> 2;
#pragma unroll
                for (int u = 0; u < 4; ++u) {
                    const int r = rbase + u;       // wave-uniform
                    float v0 = 0.f, v1 = 0.f, v2 = 0.f;
                    if (r < Kk) {
                        const int ky = r / KW, kx = r - ky * KW;
                        float offy = OMb[(size_t)(2 * r) * HOWO + gn2];
                        float offx = OMb[(size_t)(2 * r + 1) * HOWO + gn2];
                        float ml   = OMb[(size_t)(2 * Kk + r) * HOWO + gn2];
                        float mask = 1.f / (1.f + expf(-ml));
                        float ys = (float)(ho2 * STR - PAD + ky) + offy;
                        float xs = (float)(wo2 * STR - PAD + kx) + offx;
                        float y0f = floorf(ys), x0f = floorf(xs);
                        float dy = ys - y0f, dx = xs - x0f;
                        int y0 = (int)y0f, x0 = (int)x0f;
                        int yc0 = min(max(y0, 0), H - 1);
                        int yc1 = min(max(y0 + 1, 0), H - 1);
                        int xc0 = min(max(x0, 0), W - 1);
                        int xc1 = min(max(x0 + 1, 0), W - 1);
                        bool y0ok = (y0 >= 0) & (y0 < H), y1ok = (y0 + 1 >= 0) & (y0 + 1 < H);
                        bool x0ok = (x0 >= 0) & (x0 < W), x1ok = (x0 + 1 >= 0) & (x0 + 1 < W);
                        float w00 = (y0ok && x0ok) ? (1.f - dy) * (1.f - dx) * mask : 0.f;
                        float w01 = (y0ok && x1ok) ? (1.f - dy) * dx * mask : 0.f;
                        float w10 = (y1ok && x0ok) ? dy * (1.f - dx) * mask : 0.f;
                        float w11 = (y1ok && x1ok) ? dy * dx * mask : 0.f;
                        int base = yc0 * W + xc0;
                        int dxs  = xc1 - xc0;
                        int dys  = (yc1 - yc0) ? W : 0;
                        float cc[12];
#pragma unroll
                        for (int ci = 0; ci < 3; ++ci) {
                            const float* img = Xb + (size_t)ci * HWc;
                            cc[ci * 4 + 0] = img[base];
                            cc[ci * 4 + 1] = img[base + dxs];
                            cc[ci * 4 + 2] = img[base + dys];
                            cc[ci * 4 + 3] = img[base + dys + dxs];
                        }
                        v0 = w00 * cc[0] + w01 * cc[1] + w10 * cc[2]  + w11 * cc[3];
                        v1 = w00 * cc[4] + w01 * cc[5] + w10 * cc[6]  + w11 * cc[7];
                        v2 = w00 * cc[8] + w01 * cc[9] + w10 * cc[10] + w11 * cc[11];
                    }
                    tmp[u * 4 + 0] = f2bf(v0);
                    tmp[u * 4 + 1] = f2bf(v1);
                    tmp[u * 4 + 2] = f2bf(v2);
                    tmp[u * 4 + 3] = 0;
                }
            } else if constexpr (M0R) {
                const int ci = (k0 >> 4) + bkc;
                const float* img = Xb + (size_t)ci * HWc;
                float raw[16];
#pragma unroll
                for (int j = 0; j < 16; ++j) raw[j] = img[rix[j] < 0 ? 0 : rix[j]];
#pragma unroll
                for (int j = 0; j < 16; ++j) tmp[j] = rix[j] < 0 ? (unsigned short)0 : f2bf(raw[j]);
            } else {
                // MLUT: batched idx reads then unconditional clamped gathers
                int idxs[16], cis[16];
#pragma unroll
                for (int j = 0; j < 16; ++j) {
                    int gk = k0 + bkc * 16 + j;
                    int ci = (Kk == 16) ? (gk >> 4) : gk / Kk;
                    int r  = gk - ci * Kk;
                    int idx = MI0[bn2 * KPAD + r];
                    if (KGUARD && gk >= Ktot) idx = -1;
                    idxs[j] = idx; cis[j] = ci;
                }
                float raw[16];
#pragma unroll
                for (int j = 0; j < 16; ++j)
                    raw[j] = Xb[(size_t)cis[j] * HWc + (idxs[j] < 0 ? 0 : idxs[j])];
#pragma unroll
                for (int j = 0; j < 16; ++j)
                    tmp[j] = idxs[j] < 0 ? (unsigned short)0 : f2bf(raw[j]);
            }
            short8 s0, s1;
#pragma unroll
            for (int j = 0; j < 8; ++j) { s0[j] = (short)tmp[j]; s1[j] = (short)tmp[8 + j]; }
            const int g0 = (bkc * 2)     ^ (bn2 & 7);
            const int g1 = (bkc * 2 + 1) ^ (bn2 & 7);
            *(short8*)&Bs[bn2][g0 * 8] = s0;
            *(short8*)&Bs[bn2][g1 * 8] = s1;
        }
        __syncthreads();   // drains vmcnt (DMA) + lgkmcnt before MFMA reads

        // ---- MFMA: wave computes MT x 16(m) x 64(n), K=64
        {
            const int mrow = wave * 16 + l16;
#pragma unroll
            for (int kk = 0; kk < 2; ++kk) {
                const int kg = kk * 4 + quad;
                short8 a[MT];
#pragma unroll
                for (int s = 0; s < MT; ++s)
                    a[s] = *(const short8*)&As[s * 64 + mrow][((kg ^ (mrow & 7)) * 8)];
#pragma unroll
                for (int t = 0; t < 4; ++t) {
                    const int ncol = t * 16 + l16;
                    short8 b = *(const short8*)&Bs[ncol][((kg ^ (ncol & 7)) * 8)];
#pragma unroll
                    for (int s = 0; s < MT; ++s)
                        acc[s][t] = __builtin_amdgcn_mfma_f32_16x16x32_bf16(a[s], b, acc[s][t], 0, 0, 0);
                }
            }
        }
        __syncthreads();
    }

    // ---- epilogue: (bias +) store. D layout: row = quad*4+i, col = lane&15
#pragma unroll
    for (int s = 0; s < MT; ++s) {
#pragma unroll
        for (int t = 0; t < 4; ++t) {
            const int ng = n0 + t * 16 + l16;
#pragma unroll
            for (int i = 0; i < 4; ++i) {
                int mg = m0 + s * 64 + wave * 16 + quad * 4 + i;
                if (mg < M) {
                    float v = acc[s][t][i];
                    if constexpr (NKS == 1) v += bias[mg];
                    Outb[(size_t)mg * HOWO + ng] = v;
                }
            }
        }
    }
}

// Sum NP partial planes (stride PS) + bias -> out. One block per (z,m) row.
template<int NP>
__global__ __launch_bounds__(256) void reduce_bias_k(
    const float* __restrict__ P, size_t PS, const float* __restrict__ bias,
    float* __restrict__ out, int M, int HOWO)
{
    const int bc = blockIdx.x;          // z*M + m
    const int m  = bc % M;
    const float b = bias[m];
    const size_t off = (size_t)bc * HOWO;
    for (int i = threadIdx.x * 4; i < HOWO; i += 1024) {
        float4 a = *(const float4*)(P + off + i);
#pragma unroll
        for (int p = 1; p < NP; ++p) {
            float4 c = *(const float4*)(P + (size_t)p * PS + off + i);
            a.x += c.x; a.y += c.y; a.z += c.z; a.w += c.w;
        }
        a.x += b; a.y += b; a.z += b; a.w += b;
        *(float4*)(out + off + i) = a;
    }
}

// Instance norm over HW per (b,c) block; optional ReLU, dual-write, add-into-out.
// float4 vectorized (HW % 1024 == 0 for all call sites).
template<bool RELU, bool DUAL, bool ADDIN>
__global__ __launch_bounds__(256) void instnorm_k(
    const float* __restrict__ in, float* __restrict__ out,
    float* __restrict__ out2, int HW)
{
    const int bc = blockIdx.x;
    const float4* p4 = (const float4*)(in + (size_t)bc * HW);
    const int n4 = HW >> 2;
    float s = 0.f, ss = 0.f;
    for (int i = threadIdx.x; i < n4; i += 256) {
        float4 v = p4[i];
        s  += v.x + v.y + v.z + v.w;
        ss += v.x * v.x + v.y * v.y + v.z * v.z + v.w * v.w;
    }
    __shared__ float rs[256], rq[256];
    rs[threadIdx.x] = s; rq[threadIdx.x] = ss;
    __syncthreads();
    for (int o = 128; o > 0; o >>= 1) {
        if (threadIdx.x < o) { rs[threadIdx.x] += rs[threadIdx.x + o]; rq[threadIdx.x] += rq[threadIdx.x + o]; }
        __syncthreads();
    }
    float mean = rs[0] / (float)HW;
    float var  = rq[0] / (float)HW - mean * mean;
    float inv  = rsqrtf(var + 1e-5f);
    float4* q4  = (float4*)(out + (size_t)bc * HW);
    float4* q24 = DUAL ? (float4*)(out2 + (size_t)bc * HW) : nullptr;
    for (int i = threadIdx.x; i < n4; i += 256) {
        float4 v = p4[i];
        v.x = (v.x - mean) * inv; v.y = (v.y - mean) * inv;
        v.z = (v.z - mean) * inv; v.w = (v.w - mean) * inv;
        if (RELU) {
            v.x = fmaxf(v.x, 0.f); v.y = fmaxf(v.y, 0.f);
            v.z = fmaxf(v.z, 0.f); v.w = fmaxf(v.w, 0.f);
        }
        if (ADDIN) {
            float4 o = q4[i];
            o.x += v.x; o.y += v.y; o.z += v.z; o.w += v.w;
            q4[i] = o;
        } else {
            q4[i] = v;
            if (DUAL) q24[i] = v;
        }
    }
}

extern "C" void kernel_launch(void* const* d_in, const int* in_sizes, int n_in,
                              void* d_out, int out_size, void* d_ws, size_t ws_size,
                              hipStream_t stream)
{
    const float* x      = (const float*)d_in[0];
    const float* w_off1 = (const float*)d_in[1];
    const float* b_off1 = (const float*)d_in[2];
    const float* w1     = (const float*)d_in[3];
    const float* b1     = (const float*)d_in[4];
    const float* w_off2 = (const float*)d_in[5];
    const float* b_off2 = (const float*)d_in[6];
    const float* w2     = (const float*)d_in[7];
    const float* b2     = (const float*)d_in[8];
    const float* w_off3 = (const float*)d_in[9];
    const float* b_off3 = (const float*)d_in[10];
    const float* w3     = (const float*)d_in[11];
    const float* b3     = (const float*)d_in[12];
    const float* rwa[2] = {(const float*)d_in[13], (const float*)d_in[17]};
    const float* rba[2] = {(const float*)d_in[14], (const float*)d_in[18]};
    const float* rwb[2] = {(const float*)d_in[15], (const float*)d_in[19]};
    const float* rbb[2] = {(const float*)d_in[16], (const float*)d_in[20]};

    float* out   = (float*)d_out;
    float* h_out = out;                         // [16,256,32,32]
    float* skip2 = out + 4194304;               // [16,128,64,64]
    float* skip3 = out + 4194304 + 8388608;     // [16,256,32,32]

    // workspace layout (floats). pool regions are time-multiplexed:
    //   om1  (stage 1):   pool[0 .. 9,633,792)
    //   om2  (stage 2):   pool[0 .. 3,145,728)
    //   om3  (stage 3):   pool[3,145,728 .. 3,932,160)
    //   y1/y2 (residual): pool[0 .. 8,388,608)
    //   wprep (whole launch, bf16): pool[9,633,792 .. 11,272,192)
    // K-split partials (kp) live in the h1 region (dead after stage-2 main):
    //   up to 2 planes x 4,194,304 (or 4 x 786,432). total ws unchanged 112.2MB
    float* wsf  = (float*)d_ws;
    float* h1   = wsf;                      // 16,777,216  [16,64,128,128]
    float* pool = h1 + 16777216;
    float* om1  = pool;
    float* om2  = pool;
    float* om3  = pool + 3145728;
    float* y1   = pool;
    float* y2   = pool + 4194304;
    float* kp   = h1;                       // partial planes (stage>=3 only)
    unsigned short* wprep = (unsigned short*)(pool + 9633792);

    // ---- Weight prep: fp32 -> bf16, pre-swizzled into LDS tile image (one launch)
    {
        PrepAll pd;
        const float* srcs[NWT] = {w_off1, w1, w_off2, w2, w_off3, w3,
                                  rwa[0], rwb[0], rwa[1], rwb[1]};
        const int Ms  [NWT] = {147, 64, 48, 128, 48, 256, 256, 256, 256, 256};
        const int Kts [NWT] = {147, 196, 1024, 1024, 2048, 2048, 2304, 2304, 2304, 2304};
        const int KTs [NWT] = {192, 256, 1024, 1024, 2048, 2048, 2304, 2304, 2304, 2304};
        const int Mbs [NWT] = {128, 64, 64, 128, 64, 128, 128, 128, 128, 128};
        const int sKs [NWT] = {147, 147, 1024, 1024, 2048, 2048, 2304, 2304, 2304, 2304};
        const int prm [NWT] = {0, 1, 0, 0, 0, 0, 0, 0, 0, 0};
        int sg = 0;
        pd.startG[0] = 0;
        for (int i = 0; i < NWT; ++i) {
            pd.src[i] = srcs[i];
            pd.M[i] = Ms[i]; pd.Ktot[i] = Kts[i]; pd.KT[i] = KTs[i];
            pd.Mblk[i] = Mbs[i]; pd.srcK[i] = sKs[i]; pd.perm[i] = prm[i];
            pd.dstOff[i] = (unsigned)sg * 8u;
            int mb = (Ms[i] + Mbs[i] - 1) / Mbs[i];
            sg += mb * (KTs[i] >> 6) * Mbs[i] * 8;
            pd.startG[i + 1] = sg;
        }
        // sg == 409,600 granules == 3,276,800 ushorts
        prep_all_k<<<dim3((sg + 255) / 256), 256, 0, stream>>>(pd, wprep);
    }
    // prepped-weight tile offsets (ushorts) — must match the loop above
    const unsigned short* pw_off1 = wprep + 0;
    const unsigned short* pw1     = wprep + 49152;
    const unsigned short* pw_off2 = wprep + 65536;
    const unsigned short* pw2     = wprep + 131072;
    const unsigned short* pw_off3 = wprep + 262144;
    const unsigned short* pw3     = wprep + 393216;
    const unsigned short* prwa[2] = {wprep + 917504,  wprep + 2097152};
    const unsigned short* prwb[2] = {wprep + 1507328, wprep + 2686976};

    // ---- Stage 1: 7x7 s1 p3, Cin=3 -> 64ch @128x128 (4-batch chunks to bound om1)
    for (int c = 0; c < 4; ++c) {
        const float* xc = x + (size_t)c * 4 * 3 * 16384;
        conv_mfma<3,7,7,1,3,128,128,128,128,0,2><<<dim3(256, 2, 4), 256, 0, stream>>>(
            pw_off1, xc, nullptr, b_off1, om1, 147);
        conv_mfma<3,7,7,1,3,128,128,128,128,2,1,1><<<dim3(256, 1, 4), 256, 0, stream>>>(
            pw1, xc, om1, b1, h1 + (size_t)c * 4 * 64 * 16384, 64);
    }
    instnorm_k<true,false,false><<<16 * 64, 256, 0, stream>>>(h1, h1, nullptr, 16384);

    // ---- Stage 2: 4x4 s2 p1, 64 -> 128ch @64x64
    conv_mfma<64,4,4,2,1,128,128,64,64,0,1><<<dim3(64, 1, 16), 256, 0, stream>>>(
        pw_off2, h1, nullptr, b_off2, om2, 48);
    conv_mfma<64,4,4,2,1,128,128,64,64,2,2><<<dim3(64, 1, 16), 256, 0, stream>>>(
        pw2, h1, om2, b2, skip2, 128);
    instnorm_k<true,false,false><<<16 * 128, 256, 0, stream>>>(skip2, skip2, nullptr, 4096);

    // ---- Stage 3: 4x4 s2 p1, 128 -> 256ch @32x32  (h1 dead from here: kp = h1)
    conv_mfma<128,4,4,2,1,64,64,32,32,0,1,0,4><<<dim3(16, 4, 16), 256, 0, stream>>>(
        pw_off3, skip2, nullptr, b_off3, kp, 48);
    reduce_bias_k<4><<<16 * 48, 256, 0, stream>>>(kp, 786432, b_off3, om3, 48, 1024);
    conv_mfma<128,4,4,2,1,64,64,32,32,2,2,0,2><<<dim3(16, 4, 16), 256, 0, stream>>>(
        pw3, skip2, om3, b3, kp, 256);
    reduce_bias_k<2><<<16 * 256, 256, 0, stream>>>(kp, 4194304, b3, skip3, 256, 1024);
    instnorm_k<true,true,false><<<16 * 256, 256, 0, stream>>>(skip3, skip3, h_out, 1024);

    // ---- Residual blocks: reflect-pad 3x3, 256 -> 256 @32x32 (K-split 2)
    for (int r = 0; r < 2; ++r) {
        conv_mfma<256,3,3,1,1,32,32,32,32,1,2,0,2><<<dim3(16, 4, 16), 256, 0, stream>>>(
            prwa[r], h_out, nullptr, rba[r], kp, 256);
        reduce_bias_k<2><<<16 * 256, 256, 0, stream>>>(kp, 4194304, rba[r], y1, 256, 1024);
        instnorm_k<true,false,false><<<16 * 256, 256, 0, stream>>>(y1, y1, nullptr, 1024);
        conv_mfma<256,3,3,1,1,32,32,32,32,1,2,0,2><<<dim3(16, 4, 16), 256, 0, stream>>>(
            prwb[r], y1, nullptr, rbb[r], kp, 256);
        reduce_bias_k<2><<<16 * 256, 256, 0, stream>>>(kp, 4194304, rbb[r], y2, 256, 1024);
        instnorm_k<false,false,true><<<16 * 256, 256, 0, stream>>>(y2, h_out, nullptr, 1024);
    }
}